// Round 3
// baseline (186.487 us; speedup 1.0000x reference)
//
#include <hip/hip_runtime.h>
#include <hip/hip_bf16.h>
#include <math.h>
#include <stdint.h>

#define B_N   512
#define D_N   768
#define R_N   128
#define C_NEW 10
#define C_OLD 100
#define C_TOT 110
#define MARGIN_F    5.0f
#define VAR_FLOOR_F 1e-4f
#define BIG_F       1e6f

typedef __bf16 bf16;
typedef __bf16 bf16x4 __attribute__((ext_vector_type(4)));
typedef __bf16 bf16x8 __attribute__((ext_vector_type(8)));
typedef float  f32x4  __attribute__((ext_vector_type(4)));

__device__ __forceinline__ float cleanf(float v) { return isfinite(v) ? v : 0.0f; }

// order-preserving float->uint encode (monotone, handles negatives)
__device__ __forceinline__ unsigned encf(float f) {
    unsigned u = __float_as_uint(f);
    return (u & 0x80000000u) ? ~u : (u | 0x80000000u);
}
__device__ __forceinline__ float decf(unsigned u) {
    return (u & 0x80000000u) ? __uint_as_float(u & 0x7fffffffu) : __uint_as_float(~u);
}

// ---------------------------------------------------------------------------
// prep_T: grid 660 x 256. Transpose tile: basesT[c][r][d] (bf16) from
// bases[c][d][r] (f32) via register 4x4 micro-tiles + XOR-swizzled LDS.
// Block 0 additionally inits ominE (512 x 0xFFFFFFFF).
// ---------------------------------------------------------------------------
__global__ __launch_bounds__(256)
void prep_T(const float* __restrict__ cur_bases, const float* __restrict__ old_bases,
            bf16* __restrict__ basesT, unsigned* __restrict__ ominE)
{
    const int bid = blockIdx.x, t = threadIdx.x;
    if (bid == 0) {
        ominE[t] = 0xFFFFFFFFu;
        ominE[256 + t] = 0xFFFFFFFFu;
    }

    const int dt = bid % 6, c = bid / 6;
    const float* Bc = (c < C_NEW) ? cur_bases + (size_t)c * D_N * R_N
                                  : old_bases + (size_t)(c - C_NEW) * D_N * R_N;
    __shared__ bf16 T[128][128];
    const int d0 = dt * 128;
    const int rg  = t & 31;    // lanes consecutive -> coalesced global loads
    const int dgb = t >> 5;

    #pragma unroll
    for (int i = 0; i < 4; ++i) {
        const int dg = i * 8 + dgb;                          // d-group 0..31
        const float* src = Bc + (size_t)(d0 + dg * 4) * R_N + rg * 4;
        float4 v0 = *(const float4*)(src);
        float4 v1 = *(const float4*)(src + R_N);
        float4 v2 = *(const float4*)(src + 2 * R_N);
        float4 v3 = *(const float4*)(src + 3 * R_N);
        const float* f0 = (const float*)&v0;
        const float* f1 = (const float*)&v1;
        const float* f2 = (const float*)&v2;
        const float* f3 = (const float*)&v3;
        #pragma unroll
        for (int j = 0; j < 4; ++j) {
            const int R = rg * 4 + j;
            const int pc = dg ^ (R & 31);                    // XOR swizzle (8B granule)
            bf16x4 w;
            w[0] = (bf16)f0[j]; w[1] = (bf16)f1[j]; w[2] = (bf16)f2[j]; w[3] = (bf16)f3[j];
            *(bf16x4*)(&T[R][pc * 4]) = w;
        }
    }
    __syncthreads();

    #pragma unroll
    for (int it = 0; it < 16; ++it) {
        const int q = it * 256 + t;
        const int r = q >> 5, u = q & 31;
        const int pc = u ^ (r & 31);
        ushort4 w = *(const ushort4*)(&T[r][pc * 4]);
        *(ushort4*)(basesT + (size_t)c * R_N * D_N + (size_t)r * D_N + d0 + u * 4) = w;
    }
}

// ---------------------------------------------------------------------------
// main_all: grid 448 x 256 (XCD-bijective decode; 8 filler blocks).
// Two-pass K-loop (register-pressure fix vs R2):
//   pass A: stage sB only; accG = B^T B (gram, G stays in LDS).
//   pass B: stage sA = bf16(clean(z)-mu) (nd2 co-accum) + sB; acc1 = diff x B.
// Both passes use one-chunk register prefetch (global->reg early, reg->LDS late).
// Epilogue: sC <- coeff; par/cn; GEMM2 H=coeff*G; qsum; dist.
// New classes -> gdist[b][c]; old -> atomicMin(ominE[b]). Finalize is a
// separate kernel (kernel boundary provides cross-XCD coherence; no fences).
// ---------------------------------------------------------------------------
#define PADC 136
#define SM_A   0                       // 128x72 bf16 = 18432
#define SM_B   18432                   // 128x72 bf16 = 18432
#define SM_C   0                       // 128x136 bf16 = 34816 (overlays sA+sB)
#define SM_G   36864                   // 128x136 bf16 = 34816
#define SM_MU  71680                   // 768 f32 = 3072
#define SM_INV 74752                   // 512
#define SM_Q   75264                   // 512
#define SM_PAR 75776                   // 512
#define SM_CN  76288                   // 512
#define SM_ND  76800                   // 512
#define SM_T2  77312                   // 2048
#define SM_SZ  79360                   // -> 2 blocks/CU

__global__ __launch_bounds__(256, 2)
void main_all(const float* __restrict__ z, const bf16* __restrict__ basesT,
              const float* __restrict__ cur_vars, const float* __restrict__ old_vars,
              const float* __restrict__ cur_means, const float* __restrict__ old_means,
              float* __restrict__ gdist, unsigned* __restrict__ ominE)
{
    // XCD-bijective decode: 4 mt-blocks of a class land on one XCD.
    const int fid = blockIdx.x;
    const int c  = (fid & 7) + 8 * (fid >> 5);
    const int mt = (fid >> 3) & 3;
    if (c >= C_TOT) return;

    __shared__ __align__(16) unsigned char smem[SM_SZ];
    bf16*  sA   = (bf16*)(smem + SM_A);
    bf16*  sB   = (bf16*)(smem + SM_B);
    bf16*  sC   = (bf16*)(smem + SM_C);
    bf16*  sG   = (bf16*)(smem + SM_G);
    float* sMu  = (float*)(smem + SM_MU);
    float* sInv = (float*)(smem + SM_INV);
    float* sQ   = (float*)(smem + SM_Q);
    float* sPar = (float*)(smem + SM_PAR);
    float* sCn  = (float*)(smem + SM_CN);
    float* sNd  = (float*)(smem + SM_ND);
    float* sT2  = (float*)(smem + SM_T2);

    const int tid = threadIdx.x, wave = tid >> 6, lane = tid & 63;
    const int quad = lane >> 4, l15 = lane & 15;
    const int wr = (wave >> 1) * 64, wc = (wave & 1) * 64;

    const int b0 = mt * 128;
    const float* vars = (c < C_NEW) ? cur_vars + (size_t)c * (R_N + 1)
                                    : old_vars + (size_t)(c - C_NEW) * (R_N + 1);
    const float* mu = (c < C_NEW) ? cur_means + (size_t)c * D_N
                                  : old_means + (size_t)(c - C_NEW) * D_N;

    if (tid < 128) {
        sInv[tid] = 1.0f / fmaxf(vars[tid], VAR_FLOOR_F);
        sQ[tid] = 0.0f;
    }
    for (int i = tid; i < D_N; i += 256) sMu[i] = mu[i];

    const int srow = (tid * 8) >> 6 /*unused*/, dummy = srow;
    (void)dummy;
    const int qrow = tid >> 3 << 0;   // staging helpers computed inline below
    (void)qrow;

    const bf16* Bb = basesT + (size_t)c * R_N * D_N;
    const float* Az = z + (size_t)b0 * D_N;
    const int rb = tid >> 4, f4 = tid & 15;

    // ================= pass A: gram (accG only, sB staging only) ===========
    f32x4 accG[4][4];
    #pragma unroll
    for (int i = 0; i < 4; ++i)
        #pragma unroll
        for (int j = 0; j < 4; ++j) accG[i][j] = (f32x4)0.0f;

    uint4 pb[4];
    #pragma unroll
    for (int p = 0; p < 4; ++p) {
        int q = p * 256 + tid, row = q >> 3, u = q & 7;
        pb[p] = *(const uint4*)(Bb + (size_t)row * D_N + 0 + u * 8);
    }

    for (int kc = 0; kc < 12; ++kc) {
        __syncthreads();
        #pragma unroll
        for (int p = 0; p < 4; ++p) {
            int q = p * 256 + tid, row = q >> 3, u = q & 7;
            *(uint4*)(sB + row * 72 + u * 8) = pb[p];
        }
        if (kc < 11) {
            #pragma unroll
            for (int p = 0; p < 4; ++p) {
                int q = p * 256 + tid, row = q >> 3, u = q & 7;
                pb[p] = *(const uint4*)(Bb + (size_t)row * D_N + (kc + 1) * 64 + u * 8);
            }
        }
        __syncthreads();
        #pragma unroll
        for (int kk = 0; kk < 64; kk += 32) {
            bf16x8 afB[4], bgB[4];
            #pragma unroll
            for (int i = 0; i < 4; ++i) afB[i] = *(const bf16x8*)(sB + (wr + 16 * i + l15) * 72 + kk + quad * 8);
            #pragma unroll
            for (int j = 0; j < 4; ++j) bgB[j] = *(const bf16x8*)(sB + (wc + 16 * j + l15) * 72 + kk + quad * 8);
            #pragma unroll
            for (int i = 0; i < 4; ++i)
                #pragma unroll
                for (int j = 0; j < 4; ++j)
                    accG[i][j] = __builtin_amdgcn_mfma_f32_16x16x32_bf16(afB[i], bgB[j], accG[i][j], 0, 0, 0);
        }
    }
    // G -> sG (separate LDS region; accG regs free after this)
    #pragma unroll
    for (int i = 0; i < 4; ++i)
        #pragma unroll
        for (int j = 0; j < 4; ++j)
            #pragma unroll
            for (int reg = 0; reg < 4; ++reg)
                sG[(wr + 16 * i + quad * 4 + reg) * PADC + wc + 16 * j + l15] = (bf16)accG[i][j][reg];

    // ================= pass B: coeff = diff x B (sA + sB staging) ==========
    f32x4 acc1[4][4];
    #pragma unroll
    for (int i = 0; i < 4; ++i)
        #pragma unroll
        for (int j = 0; j < 4; ++j) acc1[i][j] = (f32x4)0.0f;
    float nd2p[8];
    #pragma unroll
    for (int p = 0; p < 8; ++p) nd2p[p] = 0.f;

    float4 pa[8];
    #pragma unroll
    for (int p = 0; p < 4; ++p) {
        int q = p * 256 + tid, row = q >> 3, u = q & 7;
        pb[p] = *(const uint4*)(Bb + (size_t)row * D_N + 0 + u * 8);
    }
    #pragma unroll
    for (int p = 0; p < 8; ++p) {
        int row = p * 16 + rb;
        pa[p] = *(const float4*)(Az + (size_t)row * D_N + 0 + f4 * 4);
    }

    for (int kc = 0; kc < 12; ++kc) {
        const int k0 = kc * 64;
        __syncthreads();
        #pragma unroll
        for (int p = 0; p < 4; ++p) {
            int q = p * 256 + tid, row = q >> 3, u = q & 7;
            *(uint4*)(sB + row * 72 + u * 8) = pb[p];
        }
        {
            float4 m4 = *(const float4*)(sMu + k0 + f4 * 4);
            #pragma unroll
            for (int p = 0; p < 8; ++p) {
                int row = p * 16 + rb;
                float d0 = cleanf(pa[p].x) - m4.x;
                float d1 = cleanf(pa[p].y) - m4.y;
                float d2 = cleanf(pa[p].z) - m4.z;
                float d3 = cleanf(pa[p].w) - m4.w;
                nd2p[p] += d0 * d0 + d1 * d1 + d2 * d2 + d3 * d3;
                bf16x4 w;
                w[0] = (bf16)d0; w[1] = (bf16)d1; w[2] = (bf16)d2; w[3] = (bf16)d3;
                *(bf16x4*)(sA + row * 72 + f4 * 4) = w;
            }
        }
        if (kc < 11) {
            #pragma unroll
            for (int p = 0; p < 4; ++p) {
                int q = p * 256 + tid, row = q >> 3, u = q & 7;
                pb[p] = *(const uint4*)(Bb + (size_t)row * D_N + (kc + 1) * 64 + u * 8);
            }
            #pragma unroll
            for (int p = 0; p < 8; ++p) {
                int row = p * 16 + rb;
                pa[p] = *(const float4*)(Az + (size_t)row * D_N + (kc + 1) * 64 + f4 * 4);
            }
        }
        __syncthreads();
        #pragma unroll
        for (int kk = 0; kk < 64; kk += 32) {
            bf16x8 afA[4], bgB[4];
            #pragma unroll
            for (int i = 0; i < 4; ++i) afA[i] = *(const bf16x8*)(sA + (wr + 16 * i + l15) * 72 + kk + quad * 8);
            #pragma unroll
            for (int j = 0; j < 4; ++j) bgB[j] = *(const bf16x8*)(sB + (wc + 16 * j + l15) * 72 + kk + quad * 8);
            #pragma unroll
            for (int i = 0; i < 4; ++i)
                #pragma unroll
                for (int j = 0; j < 4; ++j)
                    acc1[i][j] = __builtin_amdgcn_mfma_f32_16x16x32_bf16(afA[i], bgB[j], acc1[i][j], 0, 0, 0);
        }
    }

    // nd2 per-row: reduce over the 16-lane group sharing a row
    #pragma unroll
    for (int p = 0; p < 8; ++p) {
        float s = nd2p[p];
        s += __shfl_xor(s, 1, 64); s += __shfl_xor(s, 2, 64);
        s += __shfl_xor(s, 4, 64); s += __shfl_xor(s, 8, 64);
        if (l15 == 0) sNd[p * 16 + rb] = s;
    }
    __syncthreads();   // sA/sB readers done; sNd complete

    // coeff -> sC (overlays sA/sB)
    #pragma unroll
    for (int i = 0; i < 4; ++i)
        #pragma unroll
        for (int j = 0; j < 4; ++j)
            #pragma unroll
            for (int reg = 0; reg < 4; ++reg)
                sC[(wr + 16 * i + quad * 4 + reg) * PADC + wc + 16 * j + l15] = (bf16)acc1[i][j][reg];
    __syncthreads();

    // par / cnorm per row (from bf16 coeff)
    {
        int row = tid >> 1, half = tid & 1;
        float par = 0.f, cn = 0.f;
        #pragma unroll
        for (int m = 0; m < 8; ++m) {
            bf16x8 v = *(const bf16x8*)(sC + row * PADC + half * 64 + m * 8);
            #pragma unroll
            for (int e = 0; e < 8; ++e) {
                float f = (float)v[e];
                int col = half * 64 + m * 8 + e;
                cn  += f * f;
                par += f * f * sInv[col];
            }
        }
        sT2[tid] = par;
        sT2[256 + tid] = cn;
    }
    __syncthreads();
    if (tid < 128) {
        sPar[tid] = sT2[tid * 2] + sT2[tid * 2 + 1];
        sCn[tid]  = sT2[256 + tid * 2] + sT2[256 + tid * 2 + 1];
    }

    // GEMM2: H = coeff * G (K=128, G from LDS)
    f32x4 acc2[4][4];
    #pragma unroll
    for (int i = 0; i < 4; ++i)
        #pragma unroll
        for (int j = 0; j < 4; ++j) acc2[i][j] = (f32x4)0.0f;
    #pragma unroll
    for (int kc = 0; kc < 128; kc += 32) {
        bf16x8 af[4], bg[4];
        #pragma unroll
        for (int i = 0; i < 4; ++i) af[i] = *(const bf16x8*)(sC + (wr + 16 * i + l15) * PADC + kc + quad * 8);
        #pragma unroll
        for (int j = 0; j < 4; ++j) bg[j] = *(const bf16x8*)(sG + (wc + 16 * j + l15) * PADC + kc + quad * 8);
        #pragma unroll
        for (int i = 0; i < 4; ++i)
            #pragma unroll
            for (int j = 0; j < 4; ++j)
                acc2[i][j] = __builtin_amdgcn_mfma_f32_16x16x32_bf16(af[i], bg[j], acc2[i][j], 0, 0, 0);
    }

    // qsum[row] = sum_s H[row][s] * coeff[row][s]
    #pragma unroll
    for (int i = 0; i < 4; ++i)
        #pragma unroll
        for (int reg = 0; reg < 4; ++reg) {
            float qp = 0.f;
            #pragma unroll
            for (int j = 0; j < 4; ++j) qp += acc2[i][j][reg] * acc1[i][j][reg];
            qp += __shfl_xor(qp, 1, 64);
            qp += __shfl_xor(qp, 2, 64);
            qp += __shfl_xor(qp, 4, 64);
            qp += __shfl_xor(qp, 8, 64);
            if (l15 == 0) atomicAdd(&sQ[wr + 16 * i + quad * 4 + reg], qp);
        }
    __syncthreads();

    // final dist per row
    if (tid < 128) {
        int b = b0 + tid;
        float res = fmaxf(vars[R_N], VAR_FLOOR_F);
        float dist = (sPar[tid] + (sNd[tid] - 2.0f * sCn[tid] + sQ[tid]) / res) / (float)D_N;
        if (!isfinite(dist)) dist = BIG_F;
        if (c < C_NEW) {
            gdist[(size_t)b * C_NEW + c] = dist;
        } else {
            atomicMin(ominE + b, encf(dist));
        }
    }
}

// ---------------------------------------------------------------------------
// finalize: single block, 512 threads (one per batch row). old_min from ominE
// (1 load), own dist from 512x10 gdist; per-class sums in LDS, stage2 fused.
// ---------------------------------------------------------------------------
__global__ __launch_bounds__(512)
void finalize(const float* __restrict__ gdist, const unsigned* __restrict__ ominE,
              const int* __restrict__ labels, const int* __restrict__ ncid,
              float* __restrict__ out)
{
    __shared__ float acc[C_NEW * 4];
    __shared__ int sNcid[C_NEW];
    const int t = threadIdx.x;
    if (t < C_NEW * 4) acc[t] = 0.f;
    if (t < C_NEW) sNcid[t] = ncid[t];
    __syncthreads();

    {
        float mn = decf(ominE[t]);
        const int lab = labels[t];
        #pragma unroll
        for (int k = 0; k < C_NEW; ++k) {
            if (lab == sNcid[k]) {
                int col = min(max(sNcid[k], 0), C_NEW - 1);
                float ow = gdist[(size_t)t * C_NEW + col];
                atomicAdd(&acc[k * 4 + 0], 1.0f);
                atomicAdd(&acc[k * 4 + 1], fmaxf(0.0f, MARGIN_F + ow - mn));
                atomicAdd(&acc[k * 4 + 2], ow);
                atomicAdd(&acc[k * 4 + 3], mn);
            }
        }
    }
    __syncthreads();

    if (t == 0) {
        float total = 0.f, own = 0.f, old = 0.f, nv = 0.f;
        #pragma unroll
        for (int k = 0; k < C_NEW; ++k) {
            float cnt = acc[k * 4 + 0];
            float den = fmaxf(cnt, 1.0f);
            if (cnt > 0.f) {
                nv += 1.f;
                total += acc[k * 4 + 1] / den;
                own   += acc[k * 4 + 2] / den;
                old   += acc[k * 4 + 3] / den;
            }
        }
        float nvd = fmaxf(nv, 1.0f);
        out[0] = total / nvd;
        out[1] = own / nvd;
        out[2] = old / nvd;
    }
}

// ---------------------------------------------------------------------------
// workspace layout (bytes):
//   gdist  @ 0      : 20480   (512 x 10 f32, new classes only)
//   ominE  @ 20480  : 2048    (512 encoded old-min; init by prep_T blk 0)
//   basesT @ 22528  : 21626880 -> total ~21.6 MB
// ---------------------------------------------------------------------------
extern "C" void kernel_launch(void* const* d_in, const int* in_sizes, int n_in,
                              void* d_out, int out_size, void* d_ws, size_t ws_size,
                              hipStream_t stream)
{
    const float* features  = (const float*)d_in[0];
    const int*   labels    = (const int*)d_in[1];
    const int*   ncid      = (const int*)d_in[2];
    const float* cur_means = (const float*)d_in[3];
    const float* cur_bases = (const float*)d_in[4];
    const float* cur_vars  = (const float*)d_in[5];
    const float* old_means = (const float*)d_in[6];
    const float* old_bases = (const float*)d_in[7];
    const float* old_vars  = (const float*)d_in[8];

    unsigned char* ws = (unsigned char*)d_ws;
    float*    gdist  = (float*)(ws + 0);
    unsigned* ominE  = (unsigned*)(ws + 20480);
    bf16*     basesT = (bf16*) (ws + 22528);

    prep_T<<<dim3(6 * C_TOT), dim3(256), 0, stream>>>(cur_bases, old_bases,
                                                      basesT, ominE);
    main_all<<<dim3(448), dim3(256), 0, stream>>>(features, basesT,
                                                  cur_vars, old_vars,
                                                  cur_means, old_means,
                                                  gdist, ominE);
    finalize<<<dim3(1), dim3(512), 0, stream>>>(gdist, ominE, labels, ncid,
                                                (float*)d_out);
}

// Round 4
// 158.769 us; speedup vs baseline: 1.1746x; 1.1746x over previous
//
#include <hip/hip_runtime.h>
#include <hip/hip_bf16.h>
#include <math.h>
#include <stdint.h>

#define B_N   512
#define D_N   768
#define R_N   128
#define C_NEW 10
#define C_OLD 100
#define C_TOT 110
#define MARGIN_F    5.0f
#define VAR_FLOOR_F 1e-4f
#define BIG_F       1e6f

typedef __bf16 bf16;
typedef __bf16 bf16x4 __attribute__((ext_vector_type(4)));
typedef __bf16 bf16x8 __attribute__((ext_vector_type(8)));
typedef float  f32x4  __attribute__((ext_vector_type(4)));

__device__ __forceinline__ float cleanf(float v) { return isfinite(v) ? v : 0.0f; }

// order-preserving float->uint encode (monotone, handles negatives)
__device__ __forceinline__ unsigned encf(float f) {
    unsigned u = __float_as_uint(f);
    return (u & 0x80000000u) ? ~u : (u | 0x80000000u);
}
__device__ __forceinline__ float decf(unsigned u) {
    return (u & 0x80000000u) ? __uint_as_float(u & 0x7fffffffu) : __uint_as_float(~u);
}

// ---------------------------------------------------------------------------
// prep_gram: grid 770 x 256.
//  [0,110):   gram blocks — G[c] = B_c^T B_c (bf16) computed straight from the
//             f32 bases via per-chunk LDS transpose (independent of basesT, so
//             it can share this dispatch). Block 0 also inits ominE.
//  [110,770): transpose blocks — basesT[c][r][d] (bf16) from bases[c][d][r]
//             via register 4x4 micro-tiles + XOR-swizzled LDS.
// ---------------------------------------------------------------------------
__global__ __launch_bounds__(256, 2)
void prep_gram(const float* __restrict__ cur_bases, const float* __restrict__ old_bases,
               bf16* __restrict__ basesT, bf16* __restrict__ G,
               unsigned* __restrict__ ominE)
{
    const int bid = blockIdx.x, t = threadIdx.x;
    __shared__ __align__(16) unsigned char lds[32768 + 512];

    if (bid < C_TOT) {
        // ---------------- gram path ----------------
        if (bid == 0) {
            ominE[t] = 0xFFFFFFFFu;
            ominE[256 + t] = 0xFFFFFFFFu;
        }
        const int c = bid;
        const float* Bc = (c < C_NEW) ? cur_bases + (size_t)c * D_N * R_N
                                      : old_bases + (size_t)(c - C_NEW) * D_N * R_N;
        bf16* sT = (bf16*)lds;                 // [128][72]
        const int wave = t >> 6, lane = t & 63;
        const int quad = lane >> 4, l15 = lane & 15;
        const int wrg = (wave >> 1) * 64, wsg = (wave & 1) * 64;
        const int rg = t & 31, dgq = t >> 5;   // r-quad / d-quad-group

        f32x4 acc[4][4];
        #pragma unroll
        for (int i = 0; i < 4; ++i)
            #pragma unroll
            for (int j = 0; j < 4; ++j) acc[i][j] = (f32x4)0.0f;

        float4 pf[8];
        #pragma unroll
        for (int i = 0; i < 2; ++i) {
            const int dg = i * 8 + dgq;
            const float* src = Bc + (size_t)(dg * 4) * R_N + rg * 4;
            #pragma unroll
            for (int m = 0; m < 4; ++m) pf[i * 4 + m] = *(const float4*)(src + m * R_N);
        }

        for (int kc = 0; kc < 12; ++kc) {
            __syncthreads();
            #pragma unroll
            for (int i = 0; i < 2; ++i) {
                const int dg = i * 8 + dgq;
                #pragma unroll
                for (int j = 0; j < 4; ++j) {
                    const int R = rg * 4 + j;
                    bf16x4 w;
                    w[0] = (bf16)pf[i * 4 + 0][j];
                    w[1] = (bf16)pf[i * 4 + 1][j];
                    w[2] = (bf16)pf[i * 4 + 2][j];
                    w[3] = (bf16)pf[i * 4 + 3][j];
                    *(bf16x4*)(sT + R * 72 + dg * 4) = w;
                }
            }
            if (kc < 11) {
                #pragma unroll
                for (int i = 0; i < 2; ++i) {
                    const int dg = i * 8 + dgq;
                    const float* src = Bc + (size_t)((kc + 1) * 64 + dg * 4) * R_N + rg * 4;
                    #pragma unroll
                    for (int m = 0; m < 4; ++m) pf[i * 4 + m] = *(const float4*)(src + m * R_N);
                }
            }
            __syncthreads();
            #pragma unroll
            for (int kk = 0; kk < 64; kk += 32) {
                bf16x8 af[4], bg[4];
                #pragma unroll
                for (int i = 0; i < 4; ++i) af[i] = *(const bf16x8*)(sT + (wrg + 16 * i + l15) * 72 + kk + quad * 8);
                #pragma unroll
                for (int j = 0; j < 4; ++j) bg[j] = *(const bf16x8*)(sT + (wsg + 16 * j + l15) * 72 + kk + quad * 8);
                #pragma unroll
                for (int i = 0; i < 4; ++i)
                    #pragma unroll
                    for (int j = 0; j < 4; ++j)
                        acc[i][j] = __builtin_amdgcn_mfma_f32_16x16x32_bf16(af[i], bg[j], acc[i][j], 0, 0, 0);
            }
        }
        #pragma unroll
        for (int i = 0; i < 4; ++i)
            #pragma unroll
            for (int j = 0; j < 4; ++j)
                #pragma unroll
                for (int reg = 0; reg < 4; ++reg) {
                    int r = wrg + 16 * i + quad * 4 + reg;
                    int s = wsg + 16 * j + l15;
                    G[(size_t)c * 16384 + (size_t)r * 128 + s] = (bf16)acc[i][j][reg];
                }
        return;
    }

    // ---------------- transpose path ----------------
    const int tb = bid - C_TOT;
    const int dt = tb % 6, c = tb / 6;
    const float* Bc = (c < C_NEW) ? cur_bases + (size_t)c * D_N * R_N
                                  : old_bases + (size_t)(c - C_NEW) * D_N * R_N;
    bf16 (*T)[128] = (bf16(*)[128])lds;
    const int d0 = dt * 128;
    const int rg  = t & 31;
    const int dgb = t >> 5;

    #pragma unroll
    for (int i = 0; i < 4; ++i) {
        const int dg = i * 8 + dgb;
        const float* src = Bc + (size_t)(d0 + dg * 4) * R_N + rg * 4;
        float4 v0 = *(const float4*)(src);
        float4 v1 = *(const float4*)(src + R_N);
        float4 v2 = *(const float4*)(src + 2 * R_N);
        float4 v3 = *(const float4*)(src + 3 * R_N);
        const float* f0 = (const float*)&v0;
        const float* f1 = (const float*)&v1;
        const float* f2 = (const float*)&v2;
        const float* f3 = (const float*)&v3;
        #pragma unroll
        for (int j = 0; j < 4; ++j) {
            const int R = rg * 4 + j;
            const int pc = dg ^ (R & 31);
            bf16x4 w;
            w[0] = (bf16)f0[j]; w[1] = (bf16)f1[j]; w[2] = (bf16)f2[j]; w[3] = (bf16)f3[j];
            *(bf16x4*)(&T[R][pc * 4]) = w;
        }
    }
    __syncthreads();

    #pragma unroll
    for (int it = 0; it < 16; ++it) {
        const int q = it * 256 + t;
        const int r = q >> 5, u = q & 31;
        const int pc = u ^ (r & 31);
        ushort4 w = *(const ushort4*)(&T[r][pc * 4]);
        *(ushort4*)(basesT + (size_t)c * R_N * D_N + (size_t)r * D_N + d0 + u * 4) = w;
    }
}

// ---------------------------------------------------------------------------
// main_dist: grid 896 x 256, __launch_bounds__(256,4) -> 4 blocks/CU.
// Decode: fid = mt*112 + y*8 + x; c = x + 8y (so all 8 mt-blocks of a class
// share fid%8 == c&7 -> one XCD's L2 holds that class's basesT + G).
// Per block (mt, c), 64 batch rows:
//   K-loop (12 chunks): stage sA = bf16(clean(z)-mu) w/ nd2 co-accum + sB;
//                       acc1 = diff x B (GEMM1, 64x128).
//   Epilogue: sC <- coeff; par/cn; GEMM2 H = coeff x G with G-fragments read
//   directly from global (L2-hot); qsum from acc2 x sC; dist.
// ---------------------------------------------------------------------------
#define PADC 136
#define SM_A    0                       // 64x72 bf16 = 9216
#define SM_B    9216                    // 128x72 bf16 = 18432 -> 27648
#define SM_C    0                       // 64x136 bf16 = 17408 (overlay sA/sB)
#define SM_MU   27648                   // 768 f32 = 3072 -> 30720
#define SM_INV  30720                   // 512 -> 31232
#define SM_Q    31232                   // 256 -> 31488
#define SM_PAR  31488                   // 256 -> 31744
#define SM_CN   31744                   // 256 -> 32000
#define SM_ND   32000                   // 256 -> 32256
#define SM_T2   32256                   // 2048 -> 34304
#define SM_SZ   34304                   // 4 blocks/CU (137216 <= 163840)

__global__ __launch_bounds__(256, 4)
void main_dist(const float* __restrict__ z, const bf16* __restrict__ basesT,
               const bf16* __restrict__ G,
               const float* __restrict__ cur_vars, const float* __restrict__ old_vars,
               const float* __restrict__ cur_means, const float* __restrict__ old_means,
               float* __restrict__ gdist, unsigned* __restrict__ ominE)
{
    const int fid = blockIdx.x;
    const int x = fid & 7;
    const int y = (fid % 112) >> 3;
    const int mt = fid / 112;
    const int c = x + 8 * y;
    if (c >= C_TOT) return;

    __shared__ __align__(16) unsigned char smem[SM_SZ];
    bf16*  sA   = (bf16*)(smem + SM_A);
    bf16*  sB   = (bf16*)(smem + SM_B);
    bf16*  sC   = (bf16*)(smem + SM_C);
    float* sMu  = (float*)(smem + SM_MU);
    float* sInv = (float*)(smem + SM_INV);
    float* sQ   = (float*)(smem + SM_Q);
    float* sPar = (float*)(smem + SM_PAR);
    float* sCn  = (float*)(smem + SM_CN);
    float* sNd  = (float*)(smem + SM_ND);
    float* sT2  = (float*)(smem + SM_T2);

    const int tid = threadIdx.x, wave = tid >> 6, lane = tid & 63;
    const int quad = lane >> 4, l15 = lane & 15;
    const int wr  = (wave >> 1) * 32;      // row half of 64
    const int wcc = (wave & 1) * 64;       // col half of 128

    const int b0 = mt * 64;
    const float* vars = (c < C_NEW) ? cur_vars + (size_t)c * (R_N + 1)
                                    : old_vars + (size_t)(c - C_NEW) * (R_N + 1);
    const float* mu = (c < C_NEW) ? cur_means + (size_t)c * D_N
                                  : old_means + (size_t)(c - C_NEW) * D_N;

    if (tid < 128) sInv[tid] = 1.0f / fmaxf(vars[tid], VAR_FLOOR_F);
    if (tid < 64)  sQ[tid] = 0.0f;
    for (int i = tid; i < D_N; i += 256) sMu[i] = mu[i];

    f32x4 acc1[2][4];
    #pragma unroll
    for (int i = 0; i < 2; ++i)
        #pragma unroll
        for (int j = 0; j < 4; ++j) acc1[i][j] = (f32x4)0.0f;
    float nd2p[4];
    #pragma unroll
    for (int p = 0; p < 4; ++p) nd2p[p] = 0.f;

    const int rg4 = tid >> 4, f4 = tid & 15;
    const float* Az = z + (size_t)b0 * D_N;
    const bf16*  Bb = basesT + (size_t)c * R_N * D_N;

    for (int kc = 0; kc < 12; ++kc) {
        const int k0 = kc * 64;
        __syncthreads();
        // stage sB: full 128 r x 64 k bf16 tile from basesT (L2-hot on this XCD)
        #pragma unroll
        for (int p = 0; p < 4; ++p) {
            int q = p * 256 + tid, row = q >> 3, u = q & 7;
            *(uint4*)(sB + row * 72 + u * 8) = *(const uint4*)(Bb + (size_t)row * D_N + k0 + u * 8);
        }
        // stage sA = clean(z) - mu (f32 -> bf16), nd2 co-accum
        {
            float4 m4 = *(const float4*)(sMu + k0 + f4 * 4);
            #pragma unroll
            for (int p = 0; p < 4; ++p) {
                int row = p * 16 + rg4;
                float4 v = *(const float4*)(Az + (size_t)row * D_N + k0 + f4 * 4);
                float d0 = cleanf(v.x) - m4.x;
                float d1 = cleanf(v.y) - m4.y;
                float d2 = cleanf(v.z) - m4.z;
                float d3 = cleanf(v.w) - m4.w;
                nd2p[p] += d0 * d0 + d1 * d1 + d2 * d2 + d3 * d3;
                bf16x4 w;
                w[0] = (bf16)d0; w[1] = (bf16)d1; w[2] = (bf16)d2; w[3] = (bf16)d3;
                *(bf16x4*)(sA + row * 72 + f4 * 4) = w;
            }
        }
        __syncthreads();
        #pragma unroll
        for (int kk = 0; kk < 64; kk += 32) {
            bf16x8 af[2], bg[4];
            #pragma unroll
            for (int i = 0; i < 2; ++i) af[i] = *(const bf16x8*)(sA + (wr + 16 * i + l15) * 72 + kk + quad * 8);
            #pragma unroll
            for (int j = 0; j < 4; ++j) bg[j] = *(const bf16x8*)(sB + (wcc + 16 * j + l15) * 72 + kk + quad * 8);
            #pragma unroll
            for (int i = 0; i < 2; ++i)
                #pragma unroll
                for (int j = 0; j < 4; ++j)
                    acc1[i][j] = __builtin_amdgcn_mfma_f32_16x16x32_bf16(af[i], bg[j], acc1[i][j], 0, 0, 0);
        }
    }

    // nd2 per-row: reduce across the 16 threads sharing a row
    #pragma unroll
    for (int p = 0; p < 4; ++p) {
        float s = nd2p[p];
        s += __shfl_xor(s, 1, 64); s += __shfl_xor(s, 2, 64);
        s += __shfl_xor(s, 4, 64); s += __shfl_xor(s, 8, 64);
        if (f4 == 0) sNd[p * 16 + rg4] = s;
    }
    __syncthreads();   // all waves done reading sA/sB; sNd complete

    // coeff -> sC (overlays sA/sB region)
    #pragma unroll
    for (int i = 0; i < 2; ++i)
        #pragma unroll
        for (int j = 0; j < 4; ++j)
            #pragma unroll
            for (int reg = 0; reg < 4; ++reg)
                sC[(wr + 16 * i + quad * 4 + reg) * PADC + wcc + 16 * j + l15] = (bf16)acc1[i][j][reg];
    __syncthreads();

    // par / cnorm per row (64 rows, 4 threads/row over 32 cols each)
    {
        int row = tid >> 2, qtr = tid & 3;
        float par = 0.f, cn = 0.f;
        #pragma unroll
        for (int m = 0; m < 4; ++m) {
            bf16x8 v = *(const bf16x8*)(sC + row * PADC + qtr * 32 + m * 8);
            #pragma unroll
            for (int e = 0; e < 8; ++e) {
                float f = (float)v[e];
                int col = qtr * 32 + m * 8 + e;
                cn  += f * f;
                par += f * f * sInv[col];
            }
        }
        sT2[tid] = par;
        sT2[256 + tid] = cn;
    }
    __syncthreads();
    if (tid < 64) {
        sPar[tid] = sT2[tid * 4] + sT2[tid * 4 + 1] + sT2[tid * 4 + 2] + sT2[tid * 4 + 3];
        sCn[tid]  = sT2[256 + tid * 4] + sT2[256 + tid * 4 + 1]
                  + sT2[256 + tid * 4 + 2] + sT2[256 + tid * 4 + 3];
    }

    // GEMM2: H = coeff x G; G-fragments straight from global (L2-hot, 16B loads)
    const bf16* Gc = G + (size_t)c * 16384;
    f32x4 acc2[2][4];
    #pragma unroll
    for (int i = 0; i < 2; ++i)
        #pragma unroll
        for (int j = 0; j < 4; ++j) acc2[i][j] = (f32x4)0.0f;
    #pragma unroll
    for (int kc4 = 0; kc4 < 4; ++kc4) {
        const int kb = kc4 * 32;
        bf16x8 af[2], bg[4];
        #pragma unroll
        for (int i = 0; i < 2; ++i) af[i] = *(const bf16x8*)(sC + (wr + 16 * i + l15) * PADC + kb + quad * 8);
        #pragma unroll
        for (int j = 0; j < 4; ++j) bg[j] = *(const bf16x8*)(Gc + (size_t)(wcc + 16 * j + l15) * 128 + kb + quad * 8);
        #pragma unroll
        for (int i = 0; i < 2; ++i)
            #pragma unroll
            for (int j = 0; j < 4; ++j)
                acc2[i][j] = __builtin_amdgcn_mfma_f32_16x16x32_bf16(af[i], bg[j], acc2[i][j], 0, 0, 0);
    }

    // qsum[row] = sum_s H[row][s] * coeff[row][s]  (coeff re-read from sC)
    #pragma unroll
    for (int i = 0; i < 2; ++i)
        #pragma unroll
        for (int reg = 0; reg < 4; ++reg) {
            const int row = wr + 16 * i + quad * 4 + reg;
            float qp = 0.f;
            #pragma unroll
            for (int j = 0; j < 4; ++j)
                qp += acc2[i][j][reg] * (float)sC[row * PADC + wcc + 16 * j + l15];
            qp += __shfl_xor(qp, 1, 64);
            qp += __shfl_xor(qp, 2, 64);
            qp += __shfl_xor(qp, 4, 64);
            qp += __shfl_xor(qp, 8, 64);
            if (l15 == 0) atomicAdd(&sQ[row], qp);
        }
    __syncthreads();

    // final dist per row
    if (tid < 64) {
        int b = b0 + tid;
        float res = fmaxf(vars[R_N], VAR_FLOOR_F);
        float dist = (sPar[tid] + (sNd[tid] - 2.0f * sCn[tid] + sQ[tid]) / res) / (float)D_N;
        if (!isfinite(dist)) dist = BIG_F;
        if (c < C_NEW) {
            gdist[(size_t)b * C_NEW + c] = dist;
        } else {
            atomicMin(ominE + b, encf(dist));
        }
    }
}

// ---------------------------------------------------------------------------
// finalize: single block, 512 threads (one per batch row).
// ---------------------------------------------------------------------------
__global__ __launch_bounds__(512)
void finalize(const float* __restrict__ gdist, const unsigned* __restrict__ ominE,
              const int* __restrict__ labels, const int* __restrict__ ncid,
              float* __restrict__ out)
{
    __shared__ float acc[C_NEW * 4];
    __shared__ int sNcid[C_NEW];
    const int t = threadIdx.x;
    if (t < C_NEW * 4) acc[t] = 0.f;
    if (t < C_NEW) sNcid[t] = ncid[t];
    __syncthreads();

    {
        float mn = decf(ominE[t]);
        const int lab = labels[t];
        #pragma unroll
        for (int k = 0; k < C_NEW; ++k) {
            if (lab == sNcid[k]) {
                int col = min(max(sNcid[k], 0), C_NEW - 1);
                float ow = gdist[(size_t)t * C_NEW + col];
                atomicAdd(&acc[k * 4 + 0], 1.0f);
                atomicAdd(&acc[k * 4 + 1], fmaxf(0.0f, MARGIN_F + ow - mn));
                atomicAdd(&acc[k * 4 + 2], ow);
                atomicAdd(&acc[k * 4 + 3], mn);
            }
        }
    }
    __syncthreads();

    if (t == 0) {
        float total = 0.f, own = 0.f, old = 0.f, nv = 0.f;
        #pragma unroll
        for (int k = 0; k < C_NEW; ++k) {
            float cnt = acc[k * 4 + 0];
            float den = fmaxf(cnt, 1.0f);
            if (cnt > 0.f) {
                nv += 1.f;
                total += acc[k * 4 + 1] / den;
                own   += acc[k * 4 + 2] / den;
                old   += acc[k * 4 + 3] / den;
            }
        }
        float nvd = fmaxf(nv, 1.0f);
        out[0] = total / nvd;
        out[1] = own / nvd;
        out[2] = old / nvd;
    }
}

// ---------------------------------------------------------------------------
// workspace layout (bytes):
//   gdist  @ 0        : 20480    (512 x 10 f32, new classes only)
//   ominE  @ 20480    : 2048     (512 encoded old-min; init by prep_gram blk 0)
//   basesT @ 22528    : 21626880
//   G      @ 21649408 : 3604480  (110 x 128 x 128 bf16) -> total ~25.3 MB
// ---------------------------------------------------------------------------
extern "C" void kernel_launch(void* const* d_in, const int* in_sizes, int n_in,
                              void* d_out, int out_size, void* d_ws, size_t ws_size,
                              hipStream_t stream)
{
    const float* features  = (const float*)d_in[0];
    const int*   labels    = (const int*)d_in[1];
    const int*   ncid      = (const int*)d_in[2];
    const float* cur_means = (const float*)d_in[3];
    const float* cur_bases = (const float*)d_in[4];
    const float* cur_vars  = (const float*)d_in[5];
    const float* old_means = (const float*)d_in[6];
    const float* old_bases = (const float*)d_in[7];
    const float* old_vars  = (const float*)d_in[8];

    unsigned char* ws = (unsigned char*)d_ws;
    float*    gdist  = (float*)(ws + 0);
    unsigned* ominE  = (unsigned*)(ws + 20480);
    bf16*     basesT = (bf16*) (ws + 22528);
    bf16*     G      = (bf16*) (ws + 21649408);

    prep_gram<<<dim3(C_TOT + 6 * C_TOT), dim3(256), 0, stream>>>(
        cur_bases, old_bases, basesT, G, ominE);
    main_dist<<<dim3(896), dim3(256), 0, stream>>>(features, basesT, G,
                                                   cur_vars, old_vars,
                                                   cur_means, old_means,
                                                   gdist, ominE);
    finalize<<<dim3(1), dim3(512), 0, stream>>>(gdist, ominE, labels, ncid,
                                                (float*)d_out);
}